// Round 1
// baseline (184.560 us; speedup 1.0000x reference)
//
#include <hip/hip_runtime.h>
#include <math.h>

// Rolling stats: W=64 window over (N=262144, F=32) fp32, stride 1, VALID.
// Out row t (t < N-63): [mean(32) | std(32) | min(32) | max(32) | sum(32)].
//
// R6 structure: occupancy-first resize of the R5 LDS-staged tile.
//  - Theory: R5 (RCH=32, 95-float register arrays, ~160 VGPR) sat at
//    3 blocks/CU = 12 waves/CU, grid 1024 = 1.33 machine-waves -> thin
//    latency hiding + 1/3-occupancy tail. Kernel is ~83us vs ~30us
//    write-BW floor; compute/LDS/store-issue all <5us, so the gap is
//    latency hiding, not work.
//  - RCH=8, 64 output rows/block, stage 128 rows (16 KB LDS), 4096 blocks.
//    __launch_bounds__(256,8) forces <=64 VGPR -> 8 blocks/CU,
//    32 waves/CU, grid = exactly 2 full machine-waves (4096 = 2*8*256).
//  - Dropped ox[] register cache (outgoing row re-read from LDS: +7 cheap
//    LDS reads frees 7 VGPRs). Register arrays now smin[8]+smax[8] = 16.
//  - Extra pass-1 redundancy (64 reads per 8 outputs) is LDS-side only
//    (~11us of LDS pipe, under the 30us memory floor). Extra inter-block
//    overlap fetch (2.0x) is L3-absorbed: input is 33.6 MB << 256 MB L3.
//  - Banks: dword index = row*32 + c -> bank c; 2-way alias across
//    half-waves is free (m136). Zero conflicts, unchanged from R5.
//  - Stores: each instr = 2 aligned 128B segments (output row = 5*128B).

#define WINW 64
#define RCH 8
#define NF 32
#define CHUNKS_PER_BLK 8
#define ROWS_PER_BLK (CHUNKS_PER_BLK * RCH)  // 64 output rows per block
#define STAGE_ROWS (ROWS_PER_BLK + WINW)     // 128 input rows staged

__global__ __launch_bounds__(256, 8) void rolling_stats_kernel(
    const float* __restrict__ x, float* __restrict__ out, int N, int T_out) {
  __shared__ float tile[STAGE_ROWS * NF];  // 16384 B

  int t0_blk = blockIdx.x * ROWS_PER_BLK;

  // --- Stage: 128 rows x 32 floats = 1024 float4, 4 per thread. ---
  const float4* xv = (const float4*)x;  // row r = 8 float4s
  float4* tv = (float4*)tile;
#pragma unroll
  for (int it = 0; it < (STAGE_ROWS * NF / 4) / 256; ++it) {  // 4 iters
    int f = it * 256 + (int)threadIdx.x;
    int r = f >> 3;            // local row
    int gr = t0_blk + r;
    gr = gr < N ? gr : N - 1;  // clamp (tail block; stores guarded)
    tv[f] = xv[(size_t)gr * (NF / 4) + (f & 7)];
  }
  __syncthreads();

  // --- Per-thread sliding window over LDS. ---
  int c = (int)threadIdx.x & (NF - 1);
  int lr0 = ((int)threadIdx.x >> 5) * RCH;  // local first output row
  int t0 = t0_blk + lr0;
  const float* tc = tile + c;

  float smin[RCH], smax[RCH];  // suffix min/max of first window
  float ssum = 0.f, ssq = 0.f;
  float rmin = INFINITY, rmax = -INFINITY;

  // Pass 1: reverse scan of first window rows lr0+63 .. lr0.
#pragma unroll
  for (int j = WINW - 1; j >= RCH; --j) {
    float a = tc[(lr0 + j) * NF];
    rmin = fminf(rmin, a);
    rmax = fmaxf(rmax, a);
    ssum += a;
    ssq = fmaf(a, a, ssq);
  }
#pragma unroll
  for (int j = RCH - 1; j >= 0; --j) {
    float a = tc[(lr0 + j) * NF];
    rmin = fminf(rmin, a);
    rmax = fmaxf(rmax, a);
    ssum += a;
    ssq = fmaf(a, a, ssq);
    smin[j] = rmin;
    smax[j] = rmax;
  }

  // Pass 2: forward over the chunk's 8 outputs.
  float pmin = INFINITY, pmax = -INFINITY;
  float wsum = ssum, wsq = ssq;
  float* o = out + (size_t)t0 * (5 * NF) + c;
#pragma unroll
  for (int j = 0; j < RCH; ++j) {
    if (j > 0) {
      float bnew = tc[(lr0 + WINW - 1 + j) * NF];  // incoming row
      float aold = tc[(lr0 + j - 1) * NF];         // outgoing row (LDS)
      pmin = fminf(pmin, bnew);
      pmax = fmaxf(pmax, bnew);
      wsum += bnew - aold;
      wsq = fmaf(bnew, bnew, wsq);
      wsq = fmaf(-aold, aold, wsq);
    }
    if (t0 + j < T_out) {
      float wmin = fminf(smin[j], pmin);
      float wmax = fmaxf(smax[j], pmax);
      float mean = wsum * 0.015625f;                   // /64
      float var = fmaf(-mean, mean, wsq * 0.015625f);  // E[x^2]-E[x]^2
      var = fmaxf(var, 0.f);
      float sd = sqrtf(var);
      float* orow = o + (size_t)j * (5 * NF);
      orow[0 * NF] = mean;
      orow[1 * NF] = sd;
      orow[2 * NF] = wmin;
      orow[3 * NF] = wmax;
      orow[4 * NF] = wsum;
    }
  }
}

extern "C" void kernel_launch(void* const* d_in, const int* in_sizes, int n_in,
                              void* d_out, int out_size, void* d_ws,
                              size_t ws_size, hipStream_t stream) {
  const float* x = (const float*)d_in[0];
  float* out = (float*)d_out;
  int N = in_sizes[0] / NF;    // 262144 rows
  int T_out = N - (WINW - 1);  // 262081 output rows
  int nblocks = (T_out + ROWS_PER_BLK - 1) / ROWS_PER_BLK;  // 4096
  rolling_stats_kernel<<<nblocks, 256, 0, stream>>>(x, out, N, T_out);
}